// Round 5
// baseline (940.957 us; speedup 1.0000x reference)
//
#include <hip/hip_runtime.h>
#include <hip/hip_bf16.h>
#include <cstdint>

// Problem dims (fixed by the reference)
#define B_   8192
#define D_   1024
#define O_   1024
#define HE_  2048
#define NN_  7     // decision nodes
#define NL_  8     // leaves / experts
#define HR_  32    // router hidden
#define RC_  224   // NN_*HR_
#define K3_  3072  // router split-GEMM K (hi|hi|lo)

typedef __attribute__((ext_vector_type(2))) float f32x2;
typedef __attribute__((ext_vector_type(4))) float f32x4;
typedef __attribute__((ext_vector_type(8))) short bf16x8;
typedef __attribute__((ext_vector_type(4))) unsigned short u16x4;
typedef unsigned short u16;
typedef unsigned int u32;

__device__ __forceinline__ u16 f2bf(float f) {
  __hip_bfloat16 h = __float2bfloat16(f);
  return *reinterpret_cast<u16*>(&h);
}
__device__ __forceinline__ float bf2f(u16 u) {
  u32 v = ((u32)u) << 16;
  return *reinterpret_cast<float*>(&v);
}
__device__ __forceinline__ float gelu_exact(float v) {
  return 0.5f * v * (1.0f + erff(v * 0.7071067811865475f));
}
__device__ __forceinline__ void gload16(const void* g, void* l) {
  __builtin_amdgcn_global_load_lds(
      (const __attribute__((address_space(1))) void*)(uintptr_t)g,
      (__attribute__((address_space(3))) void*)(uintptr_t)l,
      16, 0, 0);
}
#define WAITVM(n) asm volatile("s_waitcnt vmcnt(" #n ")" ::: "memory")
#define WAITLGKM0 do { \
  asm volatile("s_waitcnt lgkmcnt(0)" ::: "memory"); \
  __builtin_amdgcn_sched_barrier(0); } while (0)

// ---- Xb3[b][3072] = [bf16(x) | bf16(x) | bf16(x - bf16(x))] ---------------
__global__ __launch_bounds__(256) void build_xb3_kernel(
    const float* __restrict__ in, u16* __restrict__ out) {
  size_t i = ((size_t)blockIdx.x * 256 + threadIdx.x) * 4;
  size_t row = i >> 10;
  int col = (int)(i & 1023);
  f32x4 f = *reinterpret_cast<const f32x4*>(in + i);
  u16x4 hi, lo;
#pragma unroll
  for (int j = 0; j < 4; j++) {
    hi[j] = f2bf(f[j]);
    lo[j] = f2bf(f[j] - bf2f(hi[j]));
  }
  u16* base = out + row * (size_t)K3_ + col;
  *reinterpret_cast<u16x4*>(base)        = hi;
  *reinterpret_cast<u16x4*>(base + 1024) = hi;
  *reinterpret_cast<u16x4*>(base + 2048) = lo;
}

// ---- Wr3[256][3072]: rows c<224 = [w_hi | w_lo | w_hi] of rW1[n][k][h] ----
__global__ __launch_bounds__(256) void build_wr3_kernel(
    const float* __restrict__ rW1, u16* __restrict__ Wr3) {
  size_t i = ((size_t)blockIdx.x * 256 + threadIdx.x) * 4;  // over 256*3072
  int c = (int)(i / K3_), k = (int)(i % K3_);
  int j = k >> 10, kk = k & 1023;
  u16x4 o;
  if (c < RC_) {
    int node = c >> 5, h = c & 31;
    const float* src = rW1 + ((size_t)node * 1024 + kk) * HR_ + h;
#pragma unroll
    for (int t = 0; t < 4; t++) {
      float f = src[t * HR_];
      u16 hi = f2bf(f);
      o[t] = (j == 1) ? f2bf(f - bf2f(hi)) : hi;
    }
  } else {
    o[0] = 0; o[1] = 0; o[2] = 0; o[3] = 0;
  }
  *reinterpret_cast<u16x4*>(Wr3 + i) = o;
}

// ------------- transpose + cvt: out[c*ldo + r] (+e*out_estride) = in[r][c] --
__global__ __launch_bounds__(256) void transpose_cvt_kernel(
    const float* __restrict__ in, u16* __restrict__ out,
    int R, int C, int ldo, long in_estride, long out_estride) {
  __shared__ __attribute__((aligned(16))) float tile[64][65];
  const float* in_e = in + (long)blockIdx.z * in_estride;
  u16* out_e = out + (long)blockIdx.z * out_estride;
  int t = threadIdx.x;
  int r0 = blockIdx.y * 64, c0 = blockIdx.x * 64;
  int cc = t & 63, rbase = t >> 6;
#pragma unroll
  for (int i = 0; i < 16; i++) {
    int rr = rbase + i * 4;
    tile[rr][cc] = in_e[(long)(r0 + rr) * C + c0 + cc];
  }
  __syncthreads();
  int r2 = (t & 31) * 2, cj = t >> 5;
#pragma unroll
  for (int i = 0; i < 8; i++) {
    int c = cj * 8 + i;
    u32 u = (u32)f2bf(tile[r2][c]) | ((u32)f2bf(tile[r2 + 1][c]) << 16);
    *reinterpret_cast<u32*>(out_e + (long)(c0 + c) * ldo + r0 + r2) = u;
  }
}

// ---- router GEMM (m97 128x128 structure): H1 = gelu(Xb3 @ Wr3^T + rb1) ----
__global__ __launch_bounds__(256, 2) void router_gemm_kernel(
    const u16* __restrict__ A, const u16* __restrict__ Bm,
    const float* __restrict__ rb1, float* __restrict__ H1) {
  __shared__ __attribute__((aligned(16))) u16 lA[128 * 32];
  __shared__ __attribute__((aligned(16))) u16 lB[128 * 32];
  int tid = threadIdx.x;
  int gid = blockIdx.x;
  int cpx = gridDim.x >> 3;
  gid = (gid & 7) * cpx + (gid >> 3);
  int bandsz = 2 * 8;
  int band = gid / bandsz, inb = gid % bandsz;
  long m0 = (long)(band * 8 + (inb & 7)) * 128;
  long n0 = (long)(inb >> 3) * 128;
  int wid = tid >> 6, lane = tid & 63;
  int wm = wid >> 1, wn = wid & 1;
  f32x4 acc[4][4];
#pragma unroll
  for (int m = 0; m < 4; m++)
#pragma unroll
    for (int n = 0; n < 4; n++) acc[m][n] = (f32x4){0.f, 0.f, 0.f, 0.f};
  int lr = lane & 15, lk = (lane >> 4) * 8;
  int srow = tid >> 2, soff = (tid & 3) * 8;
  const u16* Ab = A + m0 * K3_;
  const u16* Bb = Bm + n0 * K3_;
  for (int k0 = 0; k0 < K3_; k0 += 32) {
    gload16(Ab + (long)srow * K3_ + k0 + soff, &lA[tid * 8]);
    gload16(Ab + (long)(64 + srow) * K3_ + k0 + soff, &lA[(256 + tid) * 8]);
    gload16(Bb + (long)srow * K3_ + k0 + soff, &lB[tid * 8]);
    gload16(Bb + (long)(64 + srow) * K3_ + k0 + soff, &lB[(256 + tid) * 8]);
    __syncthreads();
    bf16x8 af[4], bfr[4];
#pragma unroll
    for (int m = 0; m < 4; m++)
      af[m] = *reinterpret_cast<const bf16x8*>(&lA[(wm * 64 + m * 16 + lr) * 32 + lk]);
#pragma unroll
    for (int n = 0; n < 4; n++)
      bfr[n] = *reinterpret_cast<const bf16x8*>(&lB[(wn * 64 + n * 16 + lr) * 32 + lk]);
#pragma unroll
    for (int m = 0; m < 4; m++)
#pragma unroll
      for (int n = 0; n < 4; n++)
        acc[m][n] = __builtin_amdgcn_mfma_f32_16x16x32_bf16(af[m], bfr[n], acc[m][n], 0, 0, 0);
    __syncthreads();
  }
  int lq = lane >> 4;
#pragma unroll
  for (int m = 0; m < 4; m++)
#pragma unroll
    for (int n = 0; n < 4; n++)
#pragma unroll
      for (int j = 0; j < 4; j++) {
        long row = m0 + wm * 64 + m * 16 + lq * 4 + j;
        long col = n0 + wn * 64 + n * 16 + lr;
        if (col < RC_)
          H1[row * RC_ + col] = gelu_exact(acc[m][n][j] + rb1[col]);
      }
}

// -------- router layer 2 + softmax + path products + top-k + renorm --------
__global__ __launch_bounds__(256) void router_logits_kernel(
    const float* __restrict__ H1, const float* __restrict__ rW2,
    const float* __restrict__ rb2, const int* __restrict__ topk_ptr,
    float* __restrict__ P) {
  int b = blockIdx.x * 256 + threadIdx.x;
  const float* hrow = H1 + (long)b * RC_;
  float dec[NN_][2];
#pragma unroll
  for (int n = 0; n < NN_; n++) {
    float l0 = rb2[n * 2], l1 = rb2[n * 2 + 1];
#pragma unroll
    for (int r4 = 0; r4 < HR_; r4 += 4) {
      f32x4 h = *reinterpret_cast<const f32x4*>(hrow + n * HR_ + r4);
#pragma unroll
      for (int j = 0; j < 4; j++) {
        l0 += h[j] * rW2[(n * HR_ + r4 + j) * 2];
        l1 += h[j] * rW2[(n * HR_ + r4 + j) * 2 + 1];
      }
    }
    float mx = fmaxf(l0, l1);
    float e0 = expf(l0 - mx), e1 = expf(l1 - mx);
    float s = e0 + e1;
    dec[n][0] = e0 / s; dec[n][1] = e1 / s;
  }
  float v[NL_];
#pragma unroll
  for (int L = 0; L < NL_; L++)
    v[L] = dec[0][L >> 2] * dec[1 + (L >> 2)][(L >> 1) & 1] * dec[3 + (L >> 1)][L & 1];
  int tk = *topk_ptr;
  float p[NL_];
  if (tk < NL_) {
    float s = 0.f;
    bool keep[NL_];
#pragma unroll
    for (int e = 0; e < NL_; e++) {
      int rank = 0;
#pragma unroll
      for (int j = 0; j < NL_; j++)
        rank += ((v[j] > v[e]) || (v[j] == v[e] && j < e)) ? 1 : 0;
      keep[e] = rank < tk;
      if (keep[e]) s += v[e];
    }
    float inv = 1.f / (s + 1e-8f);
#pragma unroll
    for (int e = 0; e < NL_; e++) p[e] = keep[e] ? v[e] * inv : 0.f;
  } else {
#pragma unroll
    for (int e = 0; e < NL_; e++) p[e] = v[e];
  }
#pragma unroll
  for (int e = 0; e < NL_; e++) P[(long)b * NL_ + e] = p[e];
}

// ---- y init: y[b][o] = sum_e P[b][e]*eb2[e][o] ----------------------------
__global__ __launch_bounds__(256) void yinit_kernel(
    const float* __restrict__ P, const float* __restrict__ eb2,
    float* __restrict__ y) {
  size_t i = ((size_t)blockIdx.x * 256 + threadIdx.x) * 4;
  size_t row = i >> 10;
  int col = (int)(i & 1023);
  f32x4 s = (f32x4){0.f, 0.f, 0.f, 0.f};
#pragma unroll
  for (int e = 0; e < NL_; e++) {
    float pe = P[row * NL_ + e];
    f32x4 w = *reinterpret_cast<const f32x4*>(eb2 + (size_t)e * O_ + col);
    s += w * pe;
  }
  *reinterpret_cast<f32x4*>(y + i) = s;
}

// ====== 4-phase/K-tile pipelined MFMA GEMM, interleaved output ownership ===
// Wave wm owns M-rows {mh*(BM/2) + wm*(BM/4) + [0,BM/4)}, wave wn owns
// N-cols {nh*128 + wn*32 + [0,32)} -> phase (mh,nh) reads EXACTLY A-half mh
// and B-half nh for every wave. Quadrant order (0,0),(0,1),(1,1),(1,0).
// Stage order per tile: A0,B0,B1,A1 (one half per phase, 4 phases ahead).
// Counted vmcnt: steady {2+a, 2a, 2+a, -}, last tile {2+a, a, 0, -}.
// MODE 0: BM=256 (a=2); out bf16 H = bf16(gelu(acc+eb1)*P[row][expert])
// MODE 2: BM=128 (a=1); out f32  y += acc   (y pre-initialized w/ bias)
template<int MODE>
__global__ __launch_bounds__(512, 2) void gemmp_kernel(
    const u16* __restrict__ A, const u16* __restrict__ Bm,
    const float* __restrict__ eb1, const float* __restrict__ P,
    void* __restrict__ outp, int lda, int ldb, int ldo,
    int tiles_n, int ncol_off, int NT) {
  constexpr int MF  = (MODE == 0) ? 8 : 4;  // m-frags per wave
  constexpr int BM  = MF * 32;              // 256 or 128
  constexpr int GA  = BM / 128;             // A gloads/thread per half (2 or 1)
  constexpr int MH2 = MF / 2;               // m-frags per half
  __shared__ __attribute__((aligned(16))) u16 lA[2][BM * 64];
  __shared__ __attribute__((aligned(16))) u16 lB[2][256 * 64];

  int tid = threadIdx.x;
  int gid = blockIdx.x;
  int cpx = gridDim.x >> 3;
  gid = (gid & 7) * cpx + (gid >> 3);       // bijective XCD swizzle (grid%8==0)
  int bandsz = tiles_n * 8;
  int band = gid / bandsz, inb = gid % bandsz;
  long m0 = (long)(band * 8 + (inb & 7)) * BM;
  long n0 = (long)(inb >> 3) * 256;
  int wid = tid >> 6, lane = tid & 63;
  int wm = wid >> 2, wn = wid & 3;          // 2M x 4N
  int lr = lane & 15, lkg = lane >> 4;

  f32x4 acc[MF][4];
#pragma unroll
  for (int m = 0; m < MF; m++)
#pragma unroll
    for (int n = 0; n < 4; n++) acc[m][n] = (f32x4){0.f, 0.f, 0.f, 0.f};

  // stage addressing: linear LDS dest, rotated-chunk source (involution pair)
  long gAo[2][GA]; int sAo[2][GA];
#pragma unroll
  for (int h = 0; h < 2; h++)
#pragma unroll
    for (int i = 0; i < GA; i++) {
      int idx = tid + i * 512;
      int r = h * (BM / 2) + (idx >> 3);      // row within full A tile
      int c = ((idx & 7) + 8 - ((r >> 1) & 7)) & 7;
      gAo[h][i] = (long)(m0 + r) * lda + c * 8;
      sAo[h][i] = h * (BM / 2) * 64 + idx * 8;
    }
  long gBo[2][2]; int sBo[2][2];
#pragma unroll
  for (int h = 0; h < 2; h++)
#pragma unroll
    for (int i = 0; i < 2; i++) {
      int idx = tid + i * 512;
      int r = h * 128 + (idx >> 3);
      int c = ((idx & 7) + 8 - ((r >> 1) & 7)) & 7;
      gBo[h][i] = (long)(n0 + r) * ldb + c * 8;
      sBo[h][i] = h * 128 * 64 + idx * 8;
    }
  // read-side fragment byte offsets (interleaved ownership)
  int foA[MF][2], foB[4][2];
#pragma unroll
  for (int m = 0; m < MF; m++) {
    int r = (m / MH2) * (BM / 2) + wm * (BM / 4) + (m % MH2) * 16 + lr;
#pragma unroll
    for (int kk = 0; kk < 2; kk++)
      foA[m][kk] = r * 128 + ((((kk * 4) + lkg + ((r >> 1) & 7)) & 7) << 4);
  }
#pragma unroll
  for (int n = 0; n < 4; n++) {
    int r = (n >> 1) * 128 + wn * 32 + (n & 1) * 16 + lr;
#pragma unroll
    for (int kk = 0; kk < 2; kk++)
      foB[n][kk] = r * 128 + ((((kk * 4) + lkg + ((r >> 1) & 7)) & 7) << 4);
  }

#define STAGE_A(nb, h, kt) do { _Pragma("unroll") \
  for (int i_ = 0; i_ < GA; i_++) \
    gload16(A + gAo[h][i_] + (long)(kt) * 64, &lA[nb][sAo[h][i_]]); } while (0)
#define STAGE_B(nb, h, kt) do { _Pragma("unroll") \
  for (int i_ = 0; i_ < 2; i_++) \
    gload16(Bm + gBo[h][i_] + (long)(kt) * 64, &lB[nb][sBo[h][i_]]); } while (0)
#define LDF(p) (*reinterpret_cast<const bf16x8*>(p))
#define MFMA_(a, b, c) __builtin_amdgcn_mfma_f32_16x16x32_bf16(a, b, c, 0, 0, 0)

  // prologue: tile 0, issue order A0,B0,B1,A1 (matches wait accounting)
  STAGE_A(0, 0, 0); STAGE_B(0, 0, 0); STAGE_B(0, 1, 0); STAGE_A(0, 1, 0);

  bf16x8 af[MH2][2], bfr[4][2];
  for (int t = 0; t < NT; ++t) {
    int cur = t & 1, nb = cur ^ 1;
    const char* pa = (const char*)lA[cur];
    const char* pb = (const char*)lB[cur];
    bool pre = (t + 1 < NT);
    // ---- phase 0 (mh=0,nh=0): needs A0,B0; allow {B1,A1} out = 2+a ----
    if constexpr (MODE == 0) WAITVM(4); else WAITVM(3);
    __builtin_amdgcn_s_barrier();
    __builtin_amdgcn_sched_barrier(0);
    if (pre) STAGE_A(nb, 0, t + 1);
#pragma unroll
    for (int m = 0; m < MH2; m++) {
      af[m][0] = LDF(pa + foA[m][0]); af[m][1] = LDF(pa + foA[m][1]);
    }
#pragma unroll
    for (int n = 0; n < 2; n++) {
      bfr[n][0] = LDF(pb + foB[n][0]); bfr[n][1] = LDF(pb + foB[n][1]);
    }
    WAITLGKM0;
    __builtin_amdgcn_s_setprio(1);
#pragma unroll
    for (int m = 0; m < MH2; m++)
#pragma unroll
      for (int n = 0; n < 2; n++) {
        acc[m][n] = MFMA_(af[m][0], bfr[n][0], acc[m][n]);
        acc[m][n] = MFMA_(af[m][1], bfr[n][1], acc[m][n]);
      }
    __builtin_amdgcn_s_setprio(0);
    __builtin_amdgcn_sched_barrier(0);
    // ---- phase 1 (mh=0,nh=1): needs B1; allow {A1,A0'} out = 2a ----
    if (pre) { if constexpr (MODE == 0) WAITVM(4); else WAITVM(2); }
    else     { if constexpr (MODE == 0) WAITVM(2); else WAITVM(1); }
    __builtin_amdgcn_s_barrier();
    __builtin_amdgcn_sched_barrier(0);
    if (pre) STAGE_B(nb, 0, t + 1);
#pragma unroll
    for (int n = 2; n < 4; n++) {
      bfr[n][0] = LDF(pb + foB[n][0]); bfr[n][1] = LDF(pb + foB[n][1]);
    }
    WAITLGKM0;
    __builtin_amdgcn_s_setprio(1);
#pragma unroll
    for (int m = 0; m < MH2; m++)
#pragma unroll
      for (int n = 2; n < 4; n++) {
        acc[m][n] = MFMA_(af[m][0], bfr[n][0], acc[m][n]);
        acc[m][n] = MFMA_(af[m][1], bfr[n][1], acc[m][n]);
      }
    __builtin_amdgcn_s_setprio(0);
    __builtin_amdgcn_sched_barrier(0);
    // ---- phase 2 (mh=1,nh=1): needs A1; allow {A0',B0'} out = a+2 ----
    if (pre) { if constexpr (MODE == 0) WAITVM(4); else WAITVM(3); }
    else WAITVM(0);
    __builtin_amdgcn_s_barrier();
    __builtin_amdgcn_sched_barrier(0);
    if (pre) STAGE_B(nb, 1, t + 1);
#pragma unroll
    for (int m = 0; m < MH2; m++) {
      af[m][0] = LDF(pa + foA[MH2 + m][0]); af[m][1] = LDF(pa + foA[MH2 + m][1]);
    }
    WAITLGKM0;
    __builtin_amdgcn_s_setprio(1);
#pragma unroll
    for (int m = 0; m < MH2; m++)
#pragma unroll
      for (int n = 2; n < 4; n++) {
        acc[MH2 + m][n] = MFMA_(af[m][0], bfr[n][0], acc[MH2 + m][n]);
        acc[MH2 + m][n] = MFMA_(af[m][1], bfr[n][1], acc[MH2 + m][n]);
      }
    __builtin_amdgcn_s_setprio(0);
    __builtin_amdgcn_sched_barrier(0);
    // ---- phase 3 (mh=1,nh=0): all operands resident/in regs ----
    __builtin_amdgcn_s_barrier();
    __builtin_amdgcn_sched_barrier(0);
    if (pre) STAGE_A(nb, 1, t + 1);
    __builtin_amdgcn_s_setprio(1);
#pragma unroll
    for (int m = 0; m < MH2; m++)
#pragma unroll
      for (int n = 0; n < 2; n++) {
        acc[MH2 + m][n] = MFMA_(af[m][0], bfr[n][0], acc[MH2 + m][n]);
        acc[MH2 + m][n] = MFMA_(af[m][1], bfr[n][1], acc[MH2 + m][n]);
      }
    __builtin_amdgcn_s_setprio(0);
    __builtin_amdgcn_sched_barrier(0);
  }
#undef STAGE_A
#undef STAGE_B
#undef LDF
#undef MFMA_

  // epilogue (interleaved ownership mapping)
#pragma unroll
  for (int m = 0; m < MF; m++)
#pragma unroll
    for (int n = 0; n < 4; n++)
#pragma unroll
      for (int j = 0; j < 4; j++) {
        long row = m0 + (m / MH2) * (BM / 2) + wm * (BM / 4) + (m % MH2) * 16
                 + lkg * 4 + j;
        long col = n0 + (n >> 1) * 128 + wn * 32 + (n & 1) * 16 + lr;
        float v = acc[m][n][j];
        if (MODE == 0) {
          long colT = col + ncol_off;
          float g = gelu_exact(v + eb1[colT]);
          float pw = P[row * NL_ + (int)(colT >> 11)];
          ((u16*)outp)[row * ldo + col] = f2bf(g * pw);
        } else {
          ((float*)outp)[row * ldo + col] += v;
        }
      }
}

extern "C" void kernel_launch(void* const* d_in, const int* in_sizes, int n_in,
                              void* d_out, int out_size, void* d_ws, size_t ws_size,
                              hipStream_t stream) {
  (void)in_sizes; (void)n_in; (void)out_size;
  const float* x   = (const float*)d_in[0];
  const float* rW1 = (const float*)d_in[1];
  const float* rb1 = (const float*)d_in[2];
  const float* rW2 = (const float*)d_in[3];
  const float* rb2 = (const float*)d_in[4];
  const float* eW1 = (const float*)d_in[5];
  const float* eb1 = (const float*)d_in[6];
  const float* eW2 = (const float*)d_in[7];
  const float* eb2 = (const float*)d_in[8];
  const int*  topk = (const int*)d_in[9];
  float* y = (float*)d_out;
  float* P = y + (size_t)B_ * O_;   // leaf_probs live in d_out tail

  char* ws = (char*)d_ws;
  u16*  Xb3 = (u16*)ws;                                   // 48 MiB
  u16*  W1t = (u16*)(ws + 50331648);                      // 32 MiB
  u16*  W2t = (u16*)(ws + 83886080);                      // 32 MiB
  char* hreg = ws + 117440512;                            // Hbuf region
  u16*  Hbuf = (u16*)hreg;
  u16*  Wr3  = (u16*)hreg;                                // dead before Hbuf use
  float* H1  = (float*)(hreg + 1572864);

  // experts-per-group: largest that fits ws (base 112MiB + EPG*32MiB)
  int epg = 1;
  {
    const size_t base = 117440512, per = 33554432;
    if      (base + 8 * per <= ws_size) epg = 8;
    else if (base + 4 * per <= ws_size) epg = 4;
    else if (base + 2 * per <= ws_size) epg = 2;
  }

  build_xb3_kernel<<<(B_ * D_) / 1024, 256, 0, stream>>>(x, Xb3);
  build_wr3_kernel<<<(256 * K3_) / 1024, 256, 0, stream>>>(rW1, Wr3);
  // W1t[e*HE+n][k] = eW1[e][k][n]
  transpose_cvt_kernel<<<dim3(HE_ / 64, D_ / 64, NL_), 256, 0, stream>>>(
      eW1, W1t, D_, HE_, D_, (long)D_ * HE_, (long)HE_ * D_);
  // W2t[o][e*HE+h] = eW2[e][h][o]
  transpose_cvt_kernel<<<dim3(O_ / 64, HE_ / 64, NL_), 256, 0, stream>>>(
      eW2, W2t, HE_, O_, NL_ * HE_, (long)HE_ * O_, (long)HE_);
  router_gemm_kernel<<<128, 256, 0, stream>>>(Xb3, Wr3, rb1, H1);
  router_logits_kernel<<<B_ / 256, 256, 0, stream>>>(H1, rW2, rb2, topk, P);
  yinit_kernel<<<(B_ * O_) / 1024, 256, 0, stream>>>(P, eb2, y);

  const int groups = NL_ / epg;
  for (int g = 0; g < groups; g++) {
    // GEMM1: [8192 x 1024] @ [epg*2048 x 1024]^T -> Hbuf (gelu, p-scaled)
    gemmp_kernel<0><<<32 * (epg * 8), 512, 0, stream>>>(
        Xb3, W1t + (size_t)g * epg * HE_ * D_, eb1, P, Hbuf,
        K3_, D_, epg * HE_, epg * 8, g * epg * HE_, 16);
    // GEMM2: [8192 x epg*2048] @ [1024 x epg*2048]^T  accumulated into y
    gemmp_kernel<2><<<64 * 4, 512, 0, stream>>>(
        Hbuf, W2t + (size_t)g * epg * HE_, nullptr, nullptr, y,
        epg * HE_, NL_ * HE_, O_, 4, 0, epg * 32);
  }
}